// Round 5
// baseline (54625.385 us; speedup 1.0000x reference)
//
#include <hip/hip_runtime.h>
#include <hip/hip_bf16.h>

// BiLSTM-CRF on MI355X.  VOCAB=50000, EMB=256, HID=512 (H=256/dir), NTAG=20, SEQ=8192.
//
// Round-5 changes (lstm_scan_mc only; rest identical to round 4):
//  * Same-XCD worker election: 64 candidate blocks; each reads XCC_ID and
//    claims a ticket; first XCD to collect 8 blocks wins; its 8 blocks run
//    the scan sharing ONE L2, everyone else exits. Cross-CU h exchange:
//    plain store into shared L2 + `global_load_dword ... sc0` poll (bypass
//    L1, hit L2) -> ~250 cy instead of ~600-900 cy LLC round trips.
//    Bounded spin falls back to agent-scope loads (correct on any XCD mix).
//  * 2-deep xg prefetch to cover ~900 cy HBM load latency.

#define S    8192
#define E    256
#define Hh   256          // per-direction hidden
#define G    1024         // 4*Hh gates
#define NT   20
#define NB   4            // blocks (CUs) per direction
#define NCAND 64          // candidate blocks for XCD election
#define NCHUNK 128        // 8192 / 64
#define CLEN   64
#define SENT 0x7FC0DEADu  // NaN bit pattern; h values are never NaN

struct ScanCtl {
    int cnt[16];          // per-XCD ticket counters
    int winner;           // winning XCD id, -1 until decided
};

__device__ __forceinline__ int get_xcc_id() {
    int x;
    asm volatile("s_getreg_b32 %0, hwreg(HW_REG_XCC_ID)" : "=s"(x));
    return x & 0xf;
}

// L2-coherent poll load: bypass L1 (sc0), served by this XCD's L2.
__device__ __forceinline__ unsigned ld_sc0_u32(const void* p) {
    unsigned v;
    asm volatile("global_load_dword %0, %1, off sc0\n"
                 "s_waitcnt vmcnt(0)"
                 : "=v"(v) : "v"(p) : "memory");
    return v;
}

// ---------------------------------------------------------------- ctl + sentinel init
__global__ __launch_bounds__(64) void init_ctl(ScanCtl* __restrict__ ctl)
{
    if (threadIdx.x < 16) ctl->cnt[threadIdx.x] = 0;
    if (threadIdx.x == 0) ctl->winner = -1;
}

__global__ __launch_bounds__(256) void sentinel_fill(unsigned int* __restrict__ lo_u)
{
    size_t base = (size_t)blockIdx.x * 1024 + threadIdx.x;
    #pragma unroll
    for (int i = 0; i < 4; ++i)
        lo_u[base + (size_t)i * 256] = SENT;      // plain stores; kernel-end flush
}

// ---------------------------------------------------------------- xg projection
__global__ __launch_bounds__(1024, 4) void xg_project(
    const int* __restrict__ sent, const float* __restrict__ embed,
    const float* __restrict__ Wih_f, const float* __restrict__ bih_f, const float* __restrict__ bhh_f,
    const float* __restrict__ Wih_b, const float* __restrict__ bih_b, const float* __restrict__ bhh_b,
    float* __restrict__ xg)                       // [2][S][G]
{
    const int tb  = blockIdx.x;                   // 0..255 (32 timesteps each)
    const int rb  = blockIdx.y;                   // 0..3
    const int dir = blockIdx.z;                   // 0..1
    const int tid = threadIdx.x;
    const int q   = tid >> 8;                     // k-quarter 0..3
    const int idx = tid & 255;
    const int r   = rb * 256 + idx;               // gate row 0..1023
    const float* Wih = dir ? Wih_b : Wih_f;

    __shared__ __align__(16) float4 xs4[32 * 64]; // 32 timesteps x 256 floats (32 KB)
    __shared__ float psum[1024];

    const int t0 = tb * 32;
    #pragma unroll
    for (int i = 0; i < 2; ++i) {
        int qq  = i * 1024 + tid;                 // 2048 float4 total
        int row = qq >> 6;
        int c4  = qq & 63;
        int widx = sent[t0 + row];
        xs4[qq] = *(const float4*)(embed + (size_t)widx * E + (size_t)c4 * 4);
    }

    float w[64];
    #pragma unroll
    for (int k = 0; k < 64; k += 4) {
        float4 v = *(const float4*)(Wih + (size_t)r * E + q * 64 + k);
        w[k] = v.x; w[k+1] = v.y; w[k+2] = v.z; w[k+3] = v.w;
    }
    float bias = 0.f;
    if (tid < 256) bias = dir ? (bih_b[r] + bhh_b[r]) : (bih_f[r] + bhh_f[r]);
    __syncthreads();

    const float* xs = (const float*)xs4 + q * 64;
    float* outb = xg + ((size_t)dir * S + t0) * G + r;
    for (int tt = 0; tt < 32; ++tt) {
        float a0 = 0.f, a1 = 0.f, a2 = 0.f, a3 = 0.f;
        #pragma unroll
        for (int k = 0; k < 64; k += 4) {
            float4 h4 = *(const float4*)(xs + tt * E + k);   // LDS broadcast
            a0 = fmaf(w[k],   h4.x, a0);
            a1 = fmaf(w[k+1], h4.y, a1);
            a2 = fmaf(w[k+2], h4.z, a2);
            a3 = fmaf(w[k+3], h4.w, a3);
        }
        psum[tid] = (a0 + a1) + (a2 + a3);
        __syncthreads();
        if (tid < 256)
            outb[(size_t)tt * G] = bias +
                ((psum[idx] + psum[idx + 256]) + (psum[idx + 512] + psum[idx + 768]));
        __syncthreads();                          // psum reused next tt
    }
}

// ---------------------------------------------------------------- LSTM scan
// NCAND candidate blocks elect 8 workers on one XCD (shared L2). Worker
// role -> (b, dir). Block (b,dir) owns h [b*64, b*64+64) = 256 gate rows.
// 1024 threads: (q, idx): gate row (idx>>6)*256 + b*64 + (idx&63),
// k-range q*64..q*64+64 (quarter-row in regs).
__global__ __launch_bounds__(1024, 4) void lstm_scan_mc(
    const float* __restrict__ xg,                 // [2][S][G]
    const float* __restrict__ Whh_f,
    const float* __restrict__ Whh_b,
    float* __restrict__ out,                      // [S][512], sentinel-prefilled
    ScanCtl* __restrict__ ctl)
{
    __shared__ int s_role;
    const int tid = threadIdx.x;

    if (tid == 0) {
        int xcc = get_xcc_id();
        int ticket = atomicAdd(&ctl->cnt[xcc], 1);           // device scope (LLC)
        if (ticket == 7) atomicCAS(&ctl->winner, -1, xcc);   // first full XCD wins
        int wn;
        do {
            wn = __hip_atomic_load(&ctl->winner, __ATOMIC_RELAXED,
                                   __HIP_MEMORY_SCOPE_AGENT);
        } while (wn == -1);
        s_role = (wn == xcc && ticket < 8) ? ticket : -1;
    }
    __syncthreads();
    const int role = s_role;
    if (role < 0) return;                                    // not a worker
    const int b   = role & 3;
    const int dir = role >> 2;

    const int q    = tid >> 8;
    const int idx  = tid & 255;
    const int gate = idx >> 6;
    const int hloc = idx & 63;
    const int hidx = b * 64 + hloc;
    const int row  = gate * Hh + hidx;
    const float* W   = dir ? Whh_b : Whh_f;
    const float* xgd = xg + (size_t)dir * S * G;

    float w[64];
    #pragma unroll
    for (int k = 0; k < 64; k += 4) {
        float4 v = *(const float4*)(W + (size_t)row * Hh + q * 64 + k);
        w[k] = v.x; w[k+1] = v.y; w[k+2] = v.z; w[k+3] = v.w;
    }

    __shared__ __align__(16) float h_lds[Hh];
    __shared__ float psum[1024];
    __shared__ float gates_lds[256];
    if (tid < Hh) h_lds[tid] = 0.f;
    float c = 0.f;

    const int t0 = dir ? (S - 1) : 0;
    const int dt = dir ? -1 : 1;
    // 2-deep xg prefetch (covers ~900 cy HBM latency across a full iteration)
    float xg_c = 0.f, xg_n1 = 0.f;
    if (tid < 256) {
        xg_c  = xgd[(size_t)t0 * G + row];
        xg_n1 = xgd[(size_t)(t0 + dt) * G + row];
    }
    __syncthreads();

    for (int s = 0; s < S; ++s) {
        const int t = t0 + dt * s;
        float xg_n2 = 0.f;
        if (tid < 256 && s + 2 < S) xg_n2 = xgd[(size_t)(t + 2 * dt) * G + row];

        // partial matvec over this thread's k-quarter (wave-uniform LDS bcast)
        const float* hh = (const float*)h_lds + q * 64;
        float a0 = 0.f, a1 = 0.f, a2 = 0.f, a3 = 0.f;
        #pragma unroll
        for (int k = 0; k < 64; k += 4) {
            float4 h4 = *(const float4*)(hh + k);
            a0 = fmaf(w[k],   h4.x, a0);
            a1 = fmaf(w[k+1], h4.y, a1);
            a2 = fmaf(w[k+2], h4.z, a2);
            a3 = fmaf(w[k+3], h4.w, a3);
        }
        psum[tid] = (a0 + a1) + (a2 + a3);
        __syncthreads();                                     // partials ready

        if (tid < 256) {
            float acc = xg_c +
                ((psum[idx] + psum[idx + 256]) + (psum[idx + 512] + psum[idx + 768]));
            float a = (gate == 2) ? tanhf(acc) : 1.f / (1.f + expf(-acc));
            gates_lds[idx] = a;
        }
        __syncthreads();                                     // gates ready

        if (tid < 64) {                                      // wave 0: cell update
            float iv = gates_lds[hloc];
            float fv = gates_lds[64 + hloc];
            float gv = gates_lds[128 + hloc];
            float ov = gates_lds[192 + hloc];
            c = fv * c + iv * gv;
            float h = ov * tanhf(c);
            // plain store -> shared (winner-XCD) L2; visible to peers' sc0 loads
            __hip_atomic_store(out + (size_t)t * 512 + dir * Hh + hidx, h,
                               __ATOMIC_RELAXED, __HIP_MEMORY_SCOPE_WORKGROUP);
            h_lds[hidx] = h;                                 // own segment direct
        }
        // poll peers' h words (written exactly once; never the NaN sentinel)
        if (s + 1 < S && tid < Hh && (tid >> 6) != b) {
            const unsigned int* srcp =
                (const unsigned int*)(out + (size_t)t * 512 + dir * Hh + tid);
            unsigned int v;
            int spins = 0;
            do {
                if (++spins <= 64) {
                    v = ld_sc0_u32(srcp);                    // L2 fast path
                } else {
                    v = __hip_atomic_load(srcp, __ATOMIC_RELAXED,
                                          __HIP_MEMORY_SCOPE_AGENT);  // LLC fallback
                }
            } while (v == SENT);
            h_lds[tid] = __uint_as_float(v);
        }
        __syncthreads();                                     // h(t) complete in LDS
        xg_c = xg_n1; xg_n1 = xg_n2;
    }
}

// ---------------------------------------------------------------- emissions
__global__ __launch_bounds__(256) void emissions_kernel(
    const float* __restrict__ lo,                 // [S][512]
    const float* __restrict__ Wout,               // [NT][512]
    const float* __restrict__ bout,
    float* __restrict__ em)                       // [S][NT]
{
    int gid = blockIdx.x * blockDim.x + threadIdx.x;
    if (gid >= S * NT) return;
    int t = gid / NT;
    int j = gid - t * NT;
    const float* x = lo + (size_t)t * 512;
    const float* w = Wout + (size_t)j * 512;
    float a0 = 0.f, a1 = 0.f, a2 = 0.f, a3 = 0.f;
    #pragma unroll 8
    for (int k = 0; k < 512; k += 4) {
        float4 xv = *(const float4*)(x + k);
        float4 wv = *(const float4*)(w + k);
        a0 = fmaf(xv.x, wv.x, a0);
        a1 = fmaf(xv.y, wv.y, a1);
        a2 = fmaf(xv.z, wv.z, a2);
        a3 = fmaf(xv.w, wv.w, a3);
    }
    em[gid] = bout[j] + ((a0 + a1) + (a2 + a3));
}

// ---------------------------------------------------------------- viterbi forward
// 64 lanes: lane = g*20 + j (g=0..2 active, lanes 60..63 spectators).
__global__ __launch_bounds__(64) void viterbi_fwd(
    const float* __restrict__ em,                 // [S][NT]
    const float* __restrict__ start_trans,
    const float* __restrict__ end_trans,
    const float* __restrict__ trans,              // [NT][NT] (from,to)
    unsigned char* __restrict__ bp,               // [S][NT]
    int* __restrict__ last_out)
{
    const int lane = threadIdx.x;
    const int g    = lane / 20;                   // 0,1,2 (3 = spectator)
    const int j    = lane - g * 20;               // to-tag (0..19 for g<3)
    const int i0   = g * 7;

    float tc[7];
    #pragma unroll
    for (int u = 0; u < 7; ++u) {
        int i = i0 + u;
        tc[u] = (g < 3 && i < 20) ? trans[i * NT + j] : -3.0e38f;
    }

    const int jj = (g < 3) ? j : 0;               // safe index for spectators
    float snew  = start_trans[jj] + em[jj];       // score(0)
    if (g == 0) bp[j] = (unsigned char)j;         // t=0: identity (never used)
    float e_cur = em[NT + jj];

    for (int t = 1; t < S; ++t) {
        float s_sub[7];
        #pragma unroll
        for (int u = 0; u < 7; ++u)
            s_sub[u] = __shfl(snew, i0 + u);      // sources are lanes 0..27
        float e_nxt = (t + 1 < S) ? em[(size_t)(t + 1) * NT + jj] : 0.f;

        float bv = s_sub[0] + tc[0];
        int   bi = i0;
        #pragma unroll
        for (int u = 1; u < 7; ++u) {
            float v = s_sub[u] + tc[u];
            if (v > bv) { bv = v; bi = i0 + u; }  // strict >: first-index in group
        }
        float v0 = __shfl(bv, jj), v1 = __shfl(bv, jj + 20), v2 = __shfl(bv, jj + 40);
        int   c0 = __shfl(bi, jj), c1 = __shfl(bi, jj + 20), c2 = __shfl(bi, jj + 40);
        float best = v0; int bidx = c0;
        if (v1 > best) { best = v1; bidx = c1; }
        if (v2 > best) { best = v2; bidx = c2; }
        snew = best + e_cur;
        if (g == 0) bp[(size_t)t * NT + j] = (unsigned char)bidx;
        e_cur = e_nxt;
    }

    float bv = __shfl(snew, 0) + end_trans[0];
    int   bi = 0;
    #pragma unroll 1
    for (int i = 1; i < 20; ++i) {
        float v = __shfl(snew, i) + end_trans[i];
        if (v > bv) { bv = v; bi = i; }
    }
    if (lane == 0) *last_out = bi;
}

// ---------------------------------------------------------------- backtrace
__global__ __launch_bounds__(64) void bt_maps(
    const unsigned char* __restrict__ bp, unsigned char* __restrict__ maps)
{
    __shared__ unsigned char lbp[CLEN * NT];
    const int c = blockIdx.x, tid = threadIdx.x;
    const unsigned* src = (const unsigned*)(bp + (size_t)c * CLEN * NT);
    unsigned* dst = (unsigned*)lbp;
    for (int q = tid; q < CLEN * NT / 4; q += 64) dst[q] = src[q];
    __syncthreads();
    if (tid < NT) {
        int x = tid;
        for (int t = CLEN - 1; t >= 0; --t) x = lbp[t * NT + x];
        maps[c * NT + tid] = (unsigned char)x;
    }
}

__global__ __launch_bounds__(64) void bt_boundary(
    const unsigned char* __restrict__ maps, const int* __restrict__ last_out,
    int* __restrict__ btags)
{
    __shared__ unsigned char m[NCHUNK * NT];
    const int tid = threadIdx.x;
    for (int q = tid; q < NCHUNK * NT; q += 64) m[q] = maps[q];
    __syncthreads();
    if (tid == 0) {
        int x = *last_out;
        btags[NCHUNK - 1] = x;
        for (int c = NCHUNK - 1; c >= 1; --c) {
            x = m[c * NT + x];
            btags[c - 1] = x;
        }
    }
}

__global__ __launch_bounds__(64) void bt_emit(
    const unsigned char* __restrict__ bp, const int* __restrict__ btags,
    int* __restrict__ path)
{
    __shared__ unsigned char lbp[CLEN * NT];
    const int c = blockIdx.x, tid = threadIdx.x;
    const unsigned* src = (const unsigned*)(bp + (size_t)c * CLEN * NT);
    unsigned* dst = (unsigned*)lbp;
    for (int q = tid; q < CLEN * NT / 4; q += 64) dst[q] = src[q];
    __syncthreads();
    if (tid == 0) {
        int x = btags[c];
        path[c * CLEN + CLEN - 1] = x;
        for (int t = CLEN - 1; t >= 1; --t) {
            x = lbp[t * NT + x];
            path[c * CLEN + t - 1] = x;
        }
    }
}

// ---------------------------------------------------------------- launcher
extern "C" void kernel_launch(void* const* d_in, const int* in_sizes, int n_in,
                              void* d_out, int out_size, void* d_ws, size_t ws_size,
                              hipStream_t stream) {
    const int*   sent   = (const int*)  d_in[0];
    const float* embed  = (const float*)d_in[1];
    const float* Wih_f  = (const float*)d_in[2];
    const float* Whh_f  = (const float*)d_in[3];
    const float* bih_f  = (const float*)d_in[4];
    const float* bhh_f  = (const float*)d_in[5];
    const float* Wih_b  = (const float*)d_in[6];
    const float* Whh_b  = (const float*)d_in[7];
    const float* bih_b  = (const float*)d_in[8];
    const float* bhh_b  = (const float*)d_in[9];
    const float* Wout   = (const float*)d_in[10];
    const float* bout   = (const float*)d_in[11];
    const float* start_trans = (const float*)d_in[12];
    const float* end_trans   = (const float*)d_in[13];
    const float* trans       = (const float*)d_in[14];
    int* path = (int*)d_out;

    char* ws = (char*)d_ws;
    size_t off = 0;
    float* xg = (float*)(ws + off); off += (size_t)2 * S * G * 4;   // 64 MB
    float* lo = (float*)(ws + off); off += (size_t)S * 512 * 4;     // 16 MB
    float* em = (float*)(ws + off); off += (size_t)S * NT * 4;      // 640 KB
    unsigned char* bp   = (unsigned char*)(ws + off); off += (size_t)S * NT;  // 160 KB
    unsigned char* maps = (unsigned char*)(ws + off); off += 4096;
    int* btags = (int*)(ws + off); off += 1024;
    int* lastp = (int*)(ws + off); off += 256;
    ScanCtl* ctl = (ScanCtl*)(ws + off); off += 256;

    init_ctl<<<dim3(1), 64, 0, stream>>>(ctl);
    sentinel_fill<<<dim3(4096), 256, 0, stream>>>((unsigned int*)lo);
    xg_project<<<dim3(S / 32, 4, 2), 1024, 0, stream>>>(
        sent, embed, Wih_f, bih_f, bhh_f, Wih_b, bih_b, bhh_b, xg);
    lstm_scan_mc<<<dim3(NCAND), 1024, 0, stream>>>(xg, Whh_f, Whh_b, lo, ctl);
    emissions_kernel<<<dim3((S * NT + 255) / 256), 256, 0, stream>>>(lo, Wout, bout, em);
    viterbi_fwd<<<dim3(1), 64, 0, stream>>>(em, start_trans, end_trans, trans, bp, lastp);
    bt_maps<<<dim3(NCHUNK), 64, 0, stream>>>(bp, maps);
    bt_boundary<<<dim3(1), 64, 0, stream>>>(maps, lastp, btags);
    bt_emit<<<dim3(NCHUNK), 64, 0, stream>>>(bp, btags, path);
}

// Round 6
// 18100.607 us; speedup vs baseline: 3.0179x; 3.0179x over previous
//
#include <hip/hip_runtime.h>
#include <hip/hip_bf16.h>

// BiLSTM-CRF on MI355X.  VOCAB=50000, EMB=256, HID=512 (H=256/dir), NTAG=20, SEQ=8192.
//
// Round-6: k-split LSTM scan. Block b of a direction owns h-chunk
// [b*64, b*64+64) and computes partial dot-products over ITS k-chunk for ALL
// 1024 gate rows (thread = row, w[64] in regs). Per step it publishes 1024
// (partial, stamp) 8-byte words (relaxed agent scope, one atomic store),
// polls 3 peer partials for the 256 rows whose h it owns, sums + activates,
// and updates only its own 64 cells. Remote h never crosses CUs, so
// activation+cell are off the pre-publish critical path: one LLC round trip
// per step total. Stamped parity-double-buffered slots; no fences, no
// sentinel refill (stamps cleared once per launch).
// Round-5's same-XCD sc0 exchange is abandoned (store never became visible
// to sc0 loads; 64 wasted spins/step).

#define S    8192
#define E    256
#define Hh   256          // per-direction hidden
#define G    1024         // 4*Hh gates
#define NT   20
#define NB   4            // blocks (CUs) per direction
#define NCHUNK 128        // 8192 / 64
#define CLEN   64

// ---------------------------------------------------------------- pbuf clear
// pbuf: [dir][parity][b][1024] x 8B = 128 KB of (value,stamp) words.
__global__ __launch_bounds__(1024) void pbuf_clear(unsigned long long* __restrict__ pbuf)
{
    int i = blockIdx.x * 1024 + threadIdx.x;
    if (i < 2 * 2 * NB * 1024) pbuf[i] = 0ull;
}

// ---------------------------------------------------------------- xg projection
__global__ __launch_bounds__(1024, 4) void xg_project(
    const int* __restrict__ sent, const float* __restrict__ embed,
    const float* __restrict__ Wih_f, const float* __restrict__ bih_f, const float* __restrict__ bhh_f,
    const float* __restrict__ Wih_b, const float* __restrict__ bih_b, const float* __restrict__ bhh_b,
    float* __restrict__ xg)                       // [2][S][G]
{
    const int tb  = blockIdx.x;                   // 0..255 (32 timesteps each)
    const int rb  = blockIdx.y;                   // 0..3
    const int dir = blockIdx.z;                   // 0..1
    const int tid = threadIdx.x;
    const int q   = tid >> 8;                     // k-quarter 0..3
    const int idx = tid & 255;
    const int r   = rb * 256 + idx;               // gate row 0..1023
    const float* Wih = dir ? Wih_b : Wih_f;

    __shared__ __align__(16) float4 xs4[32 * 64]; // 32 timesteps x 256 floats (32 KB)
    __shared__ float psum[1024];

    const int t0 = tb * 32;
    #pragma unroll
    for (int i = 0; i < 2; ++i) {
        int qq  = i * 1024 + tid;                 // 2048 float4 total
        int row = qq >> 6;
        int c4  = qq & 63;
        int widx = sent[t0 + row];
        xs4[qq] = *(const float4*)(embed + (size_t)widx * E + (size_t)c4 * 4);
    }

    float w[64];
    #pragma unroll
    for (int k = 0; k < 64; k += 4) {
        float4 v = *(const float4*)(Wih + (size_t)r * E + q * 64 + k);
        w[k] = v.x; w[k+1] = v.y; w[k+2] = v.z; w[k+3] = v.w;
    }
    float bias = 0.f;
    if (tid < 256) bias = dir ? (bih_b[r] + bhh_b[r]) : (bih_f[r] + bhh_f[r]);
    __syncthreads();

    const float* xs = (const float*)xs4 + q * 64;
    float* outb = xg + ((size_t)dir * S + t0) * G + r;
    for (int tt = 0; tt < 32; ++tt) {
        float a0 = 0.f, a1 = 0.f, a2 = 0.f, a3 = 0.f;
        #pragma unroll
        for (int k = 0; k < 64; k += 4) {
            float4 h4 = *(const float4*)(xs + tt * E + k);   // LDS broadcast
            a0 = fmaf(w[k],   h4.x, a0);
            a1 = fmaf(w[k+1], h4.y, a1);
            a2 = fmaf(w[k+2], h4.z, a2);
            a3 = fmaf(w[k+3], h4.w, a3);
        }
        psum[tid] = (a0 + a1) + (a2 + a3);
        __syncthreads();
        if (tid < 256)
            outb[(size_t)tt * G] = bias +
                ((psum[idx] + psum[idx + 256]) + (psum[idx + 512] + psum[idx + 768]));
        __syncthreads();                          // psum reused next tt
    }
}

// ---------------------------------------------------------------- LSTM scan (k-split)
// Grid (NB, 2). Thread tid = gate row. Block b: k-chunk [b*64, b*64+64),
// owns h-chunk [b*64, b*64+64). Consumer threads: (tid>>6)&3 == b (256 of
// 1024: 4 gates x 64 h), i.e. rows whose h-index falls in the own chunk.
__global__ __launch_bounds__(1024, 4) void lstm_scan_k(
    const float* __restrict__ xg,                 // [2][S][G]
    const float* __restrict__ Whh_f,
    const float* __restrict__ Whh_b,
    float* __restrict__ out,                      // [S][512]
    unsigned long long* __restrict__ pbuf)        // [2][2][NB][1024]
{
    const int b    = blockIdx.x;
    const int dir  = blockIdx.y;
    const int tid  = threadIdx.x;                 // gate row 0..1023
    const float* W   = dir ? Whh_b : Whh_f;
    const float* xgd = xg + (size_t)dir * S * G;

    float w[64];                                  // W[tid][b*64 .. b*64+64)
    #pragma unroll
    for (int k = 0; k < 64; k += 4) {
        float4 v = *(const float4*)(W + (size_t)tid * Hh + b * 64 + k);
        w[k] = v.x; w[k+1] = v.y; w[k+2] = v.z; w[k+3] = v.w;
    }

    __shared__ __align__(16) float h_lds[64];     // own h-chunk
    __shared__ float gl[256];                     // gates for own 64 h: [gate][64]
    const bool cons = (((tid >> 6) & 3) == b);
    const int  u    = tid & 63;
    const int  gate = tid >> 8;
    if (tid < 64) h_lds[tid] = 0.f;
    float c = 0.f;

    const int t0 = dir ? (S - 1) : 0;
    const int dt = dir ? -1 : 1;
    float xg_c = 0.f, xg_n1 = 0.f;                // 2-deep prefetch (cons rows only)
    if (cons) {
        xg_c  = xgd[(size_t)t0 * G + tid];
        xg_n1 = xgd[(size_t)(t0 + dt) * G + tid];
    }
    const int p0 = (b + 1) & 3, p1 = (b + 2) & 3, p2 = (b + 3) & 3;
    __syncthreads();

    for (int s = 0; s < S; ++s) {
        const int t = t0 + dt * s;
        float xg_n2 = 0.f;
        if (cons && s + 2 < S) xg_n2 = xgd[(size_t)(t + 2 * dt) * G + tid];

        // partial dot-product: own k-chunk (h via wave-uniform LDS broadcast)
        float a0 = 0.f, a1 = 0.f, a2 = 0.f, a3 = 0.f;
        #pragma unroll
        for (int k = 0; k < 64; k += 4) {
            float4 h4 = *(const float4*)(h_lds + k);
            a0 = fmaf(w[k],   h4.x, a0);
            a1 = fmaf(w[k+1], h4.y, a1);
            a2 = fmaf(w[k+2], h4.z, a2);
            a3 = fmaf(w[k+3], h4.w, a3);
        }
        const float part = (a0 + a1) + (a2 + a3);

        // publish (value, stamp) as one 8B relaxed agent-scope store
        const unsigned st = (unsigned)(s + 1);
        const size_t base = (size_t)((dir * 2) + (s & 1)) * (NB * 1024);
        unsigned long long pw =
            ((unsigned long long)st << 32) | (unsigned long long)__float_as_uint(part);
        __hip_atomic_store(&pbuf[base + (size_t)b * 1024 + tid], pw,
                           __ATOMIC_RELAXED, __HIP_MEMORY_SCOPE_AGENT);

        if (cons) {                               // consume 3 peer partials for row tid
            const unsigned long long* q0 = &pbuf[base + (size_t)p0 * 1024 + tid];
            const unsigned long long* q1 = &pbuf[base + (size_t)p1 * 1024 + tid];
            const unsigned long long* q2 = &pbuf[base + (size_t)p2 * 1024 + tid];
            unsigned long long u0, u1, u2;
            do {
                u0 = __hip_atomic_load(q0, __ATOMIC_RELAXED, __HIP_MEMORY_SCOPE_AGENT);
                u1 = __hip_atomic_load(q1, __ATOMIC_RELAXED, __HIP_MEMORY_SCOPE_AGENT);
                u2 = __hip_atomic_load(q2, __ATOMIC_RELAXED, __HIP_MEMORY_SCOPE_AGENT);
            } while ((unsigned)(u0 >> 32) != st || (unsigned)(u1 >> 32) != st ||
                     (unsigned)(u2 >> 32) != st);
            float acc = xg_c + part;
            acc += __uint_as_float((unsigned)u0);
            acc += __uint_as_float((unsigned)u1);
            acc += __uint_as_float((unsigned)u2);
            float a = (gate == 2) ? tanhf(acc) : 1.f / (1.f + expf(-acc));
            gl[gate * 64 + u] = a;
        }
        __syncthreads();                          // gates ready

        if (tid < 64) {                           // cell update, own chunk only
            float iv = gl[tid];
            float fv = gl[64 + tid];
            float gv = gl[128 + tid];
            float ov = gl[192 + tid];
            c = fv * c + iv * gv;
            float h = ov * tanhf(c);
            h_lds[tid] = h;
            out[(size_t)t * 512 + dir * Hh + b * 64 + tid] = h;   // plain store
        }
        __syncthreads();                          // h(t) ready in LDS
        xg_c = xg_n1; xg_n1 = xg_n2;
    }
}

// ---------------------------------------------------------------- emissions
__global__ __launch_bounds__(256) void emissions_kernel(
    const float* __restrict__ lo,                 // [S][512]
    const float* __restrict__ Wout,               // [NT][512]
    const float* __restrict__ bout,
    float* __restrict__ em)                       // [S][NT]
{
    int gid = blockIdx.x * blockDim.x + threadIdx.x;
    if (gid >= S * NT) return;
    int t = gid / NT;
    int j = gid - t * NT;
    const float* x = lo + (size_t)t * 512;
    const float* w = Wout + (size_t)j * 512;
    float a0 = 0.f, a1 = 0.f, a2 = 0.f, a3 = 0.f;
    #pragma unroll 8
    for (int k = 0; k < 512; k += 4) {
        float4 xv = *(const float4*)(x + k);
        float4 wv = *(const float4*)(w + k);
        a0 = fmaf(xv.x, wv.x, a0);
        a1 = fmaf(xv.y, wv.y, a1);
        a2 = fmaf(xv.z, wv.z, a2);
        a3 = fmaf(xv.w, wv.w, a3);
    }
    em[gid] = bout[j] + ((a0 + a1) + (a2 + a3));
}

// ---------------------------------------------------------------- viterbi forward
// 64 lanes: lane = g*20 + j (g=0..2 active, lanes 60..63 spectators).
__global__ __launch_bounds__(64) void viterbi_fwd(
    const float* __restrict__ em,                 // [S][NT]
    const float* __restrict__ start_trans,
    const float* __restrict__ end_trans,
    const float* __restrict__ trans,              // [NT][NT] (from,to)
    unsigned char* __restrict__ bp,               // [S][NT]
    int* __restrict__ last_out)
{
    const int lane = threadIdx.x;
    const int g    = lane / 20;                   // 0,1,2 (3 = spectator)
    const int j    = lane - g * 20;               // to-tag (0..19 for g<3)
    const int i0   = g * 7;

    float tc[7];
    #pragma unroll
    for (int u = 0; u < 7; ++u) {
        int i = i0 + u;
        tc[u] = (g < 3 && i < 20) ? trans[i * NT + j] : -3.0e38f;
    }

    const int jj = (g < 3) ? j : 0;               // safe index for spectators
    float snew  = start_trans[jj] + em[jj];       // score(0)
    if (g == 0) bp[j] = (unsigned char)j;         // t=0: identity (never used)
    float e_cur = em[NT + jj];

    for (int t = 1; t < S; ++t) {
        float s_sub[7];
        #pragma unroll
        for (int u = 0; u < 7; ++u)
            s_sub[u] = __shfl(snew, i0 + u);      // sources are lanes 0..27
        float e_nxt = (t + 1 < S) ? em[(size_t)(t + 1) * NT + jj] : 0.f;

        float bv = s_sub[0] + tc[0];
        int   bi = i0;
        #pragma unroll
        for (int u = 1; u < 7; ++u) {
            float v = s_sub[u] + tc[u];
            if (v > bv) { bv = v; bi = i0 + u; }  // strict >: first-index in group
        }
        float v0 = __shfl(bv, jj), v1 = __shfl(bv, jj + 20), v2 = __shfl(bv, jj + 40);
        int   c0 = __shfl(bi, jj), c1 = __shfl(bi, jj + 20), c2 = __shfl(bi, jj + 40);
        float best = v0; int bidx = c0;
        if (v1 > best) { best = v1; bidx = c1; }
        if (v2 > best) { best = v2; bidx = c2; }
        snew = best + e_cur;
        if (g == 0) bp[(size_t)t * NT + j] = (unsigned char)bidx;
        e_cur = e_nxt;
    }

    float bv = __shfl(snew, 0) + end_trans[0];
    int   bi = 0;
    #pragma unroll 1
    for (int i = 1; i < 20; ++i) {
        float v = __shfl(snew, i) + end_trans[i];
        if (v > bv) { bv = v; bi = i; }
    }
    if (lane == 0) *last_out = bi;
}

// ---------------------------------------------------------------- backtrace
__global__ __launch_bounds__(64) void bt_maps(
    const unsigned char* __restrict__ bp, unsigned char* __restrict__ maps)
{
    __shared__ unsigned char lbp[CLEN * NT];
    const int c = blockIdx.x, tid = threadIdx.x;
    const unsigned* src = (const unsigned*)(bp + (size_t)c * CLEN * NT);
    unsigned* dst = (unsigned*)lbp;
    for (int q = tid; q < CLEN * NT / 4; q += 64) dst[q] = src[q];
    __syncthreads();
    if (tid < NT) {
        int x = tid;
        for (int t = CLEN - 1; t >= 0; --t) x = lbp[t * NT + x];
        maps[c * NT + tid] = (unsigned char)x;
    }
}

__global__ __launch_bounds__(64) void bt_boundary(
    const unsigned char* __restrict__ maps, const int* __restrict__ last_out,
    int* __restrict__ btags)
{
    __shared__ unsigned char m[NCHUNK * NT];
    const int tid = threadIdx.x;
    for (int q = tid; q < NCHUNK * NT; q += 64) m[q] = maps[q];
    __syncthreads();
    if (tid == 0) {
        int x = *last_out;
        btags[NCHUNK - 1] = x;
        for (int c = NCHUNK - 1; c >= 1; --c) {
            x = m[c * NT + x];
            btags[c - 1] = x;
        }
    }
}

__global__ __launch_bounds__(64) void bt_emit(
    const unsigned char* __restrict__ bp, const int* __restrict__ btags,
    int* __restrict__ path)
{
    __shared__ unsigned char lbp[CLEN * NT];
    const int c = blockIdx.x, tid = threadIdx.x;
    const unsigned* src = (const unsigned*)(bp + (size_t)c * CLEN * NT);
    unsigned* dst = (unsigned*)lbp;
    for (int q = tid; q < CLEN * NT / 4; q += 64) dst[q] = src[q];
    __syncthreads();
    if (tid == 0) {
        int x = btags[c];
        path[c * CLEN + CLEN - 1] = x;
        for (int t = CLEN - 1; t >= 1; --t) {
            x = lbp[t * NT + x];
            path[c * CLEN + t - 1] = x;
        }
    }
}

// ---------------------------------------------------------------- launcher
extern "C" void kernel_launch(void* const* d_in, const int* in_sizes, int n_in,
                              void* d_out, int out_size, void* d_ws, size_t ws_size,
                              hipStream_t stream) {
    const int*   sent   = (const int*)  d_in[0];
    const float* embed  = (const float*)d_in[1];
    const float* Wih_f  = (const float*)d_in[2];
    const float* Whh_f  = (const float*)d_in[3];
    const float* bih_f  = (const float*)d_in[4];
    const float* bhh_f  = (const float*)d_in[5];
    const float* Wih_b  = (const float*)d_in[6];
    const float* Whh_b  = (const float*)d_in[7];
    const float* bih_b  = (const float*)d_in[8];
    const float* bhh_b  = (const float*)d_in[9];
    const float* Wout   = (const float*)d_in[10];
    const float* bout   = (const float*)d_in[11];
    const float* start_trans = (const float*)d_in[12];
    const float* end_trans   = (const float*)d_in[13];
    const float* trans       = (const float*)d_in[14];
    int* path = (int*)d_out;

    char* ws = (char*)d_ws;
    size_t off = 0;
    float* xg = (float*)(ws + off); off += (size_t)2 * S * G * 4;   // 64 MB
    float* lo = (float*)(ws + off); off += (size_t)S * 512 * 4;     // 16 MB
    float* em = (float*)(ws + off); off += (size_t)S * NT * 4;      // 640 KB
    unsigned char* bp   = (unsigned char*)(ws + off); off += (size_t)S * NT;  // 160 KB
    unsigned char* maps = (unsigned char*)(ws + off); off += 4096;
    int* btags = (int*)(ws + off); off += 1024;
    int* lastp = (int*)(ws + off); off += 256;
    off = (off + 255) & ~(size_t)255;
    unsigned long long* pbuf = (unsigned long long*)(ws + off); off += 2 * 2 * NB * 1024 * 8;

    pbuf_clear<<<dim3(16), 1024, 0, stream>>>(pbuf);
    xg_project<<<dim3(S / 32, 4, 2), 1024, 0, stream>>>(
        sent, embed, Wih_f, bih_f, bhh_f, Wih_b, bih_b, bhh_b, xg);
    lstm_scan_k<<<dim3(NB, 2), 1024, 0, stream>>>(xg, Whh_f, Whh_b, lo, pbuf);
    emissions_kernel<<<dim3((S * NT + 255) / 256), 256, 0, stream>>>(lo, Wout, bout, em);
    viterbi_fwd<<<dim3(1), 64, 0, stream>>>(em, start_trans, end_trans, trans, bp, lastp);
    bt_maps<<<dim3(NCHUNK), 64, 0, stream>>>(bp, maps);
    bt_boundary<<<dim3(1), 64, 0, stream>>>(maps, lastp, btags);
    bt_emit<<<dim3(NCHUNK), 64, 0, stream>>>(bp, btags, path);
}

// Round 7
// 17159.824 us; speedup vs baseline: 3.1833x; 1.0548x over previous
//
#include <hip/hip_runtime.h>
#include <hip/hip_bf16.h>

// BiLSTM-CRF on MI355X.  VOCAB=50000, EMB=256, HID=512 (H=256/dir), NTAG=20, SEQ=8192.
//
// Round-7: round-4 compute structure (NB=4 blocks/dir, 1024 thr, w[64]/thread)
// with a dual-path h exchange:
//  * fast path: workers = blocks {0,8,...,56} of a 64-block grid (round-robin
//    dispatch should co-locate them on one XCD / one shared L2). Producer
//    publishes (stamp,h) with a plain store (write-through L1 -> shared L2);
//    consumer polls with `global_load_dwordx2 ... sc0` (bypass L1, hit L2).
//  * slow path (proven rounds 2-6): agent-scope store/load through the LLC.
//  * startup handshake verifies the fast path per-block with bounded budget;
//    per-thread sticky downgrade (4096-spin budget) in the main loop makes a
//    wrong choice cost bounded time, never a hang.
// Stamped (stamp,value) u64 slots, parity double-buffered: no sentinel refill,
// replay-safe (sync buffers zeroed each launch by sync_init).

#define S    8192
#define E    256
#define Hh   256          // per-direction hidden
#define G    1024         // 4*Hh gates
#define NT   20
#define NB   4            // blocks (CUs) per direction
#define NCHUNK 128        // 8192 / 64
#define CLEN   64
#define MAGICV 0xC0FFEE00DEADBEEFull

// sync buffer layout (u64 units): hot[4][256] | slow[4][256] | hs_hot[8] | hs_slow[8] | ctr
#define SB_SLOW 1024
#define SB_HSH  2048
#define SB_HSS  2056
#define SB_CTR  2064
#define SB_SIZE 2080

__device__ __forceinline__ unsigned long long ld_sc0_u64(const unsigned long long* p) {
    unsigned long long v;
    asm volatile("global_load_dwordx2 %0, %1, off sc0\n\ts_waitcnt vmcnt(0)"
                 : "=v"(v) : "v"(p) : "memory");
    return v;
}

// ---------------------------------------------------------------- sync init
__global__ __launch_bounds__(1024) void sync_init(unsigned long long* __restrict__ sb)
{
    int i = threadIdx.x;
    sb[i] = 0ull;
    sb[1024 + i] = 0ull;
    if (i < SB_SIZE - 2048) sb[2048 + i] = 0ull;
}

// ---------------------------------------------------------------- xg projection
__global__ __launch_bounds__(1024, 4) void xg_project(
    const int* __restrict__ sent, const float* __restrict__ embed,
    const float* __restrict__ Wih_f, const float* __restrict__ bih_f, const float* __restrict__ bhh_f,
    const float* __restrict__ Wih_b, const float* __restrict__ bih_b, const float* __restrict__ bhh_b,
    float* __restrict__ xg)                       // [2][S][G]
{
    const int tb  = blockIdx.x;                   // 0..255 (32 timesteps each)
    const int rb  = blockIdx.y;                   // 0..3
    const int dir = blockIdx.z;                   // 0..1
    const int tid = threadIdx.x;
    const int q   = tid >> 8;                     // k-quarter 0..3
    const int idx = tid & 255;
    const int r   = rb * 256 + idx;               // gate row 0..1023
    const float* Wih = dir ? Wih_b : Wih_f;

    __shared__ __align__(16) float4 xs4[32 * 64]; // 32 timesteps x 256 floats (32 KB)
    __shared__ float psum[1024];

    const int t0 = tb * 32;
    #pragma unroll
    for (int i = 0; i < 2; ++i) {
        int qq  = i * 1024 + tid;                 // 2048 float4 total
        int row = qq >> 6;
        int c4  = qq & 63;
        int widx = sent[t0 + row];
        xs4[qq] = *(const float4*)(embed + (size_t)widx * E + (size_t)c4 * 4);
    }

    float w[64];
    #pragma unroll
    for (int k = 0; k < 64; k += 4) {
        float4 v = *(const float4*)(Wih + (size_t)r * E + q * 64 + k);
        w[k] = v.x; w[k+1] = v.y; w[k+2] = v.z; w[k+3] = v.w;
    }
    float bias = 0.f;
    if (tid < 256) bias = dir ? (bih_b[r] + bhh_b[r]) : (bih_f[r] + bhh_f[r]);
    __syncthreads();

    const float* xs = (const float*)xs4 + q * 64;
    float* outb = xg + ((size_t)dir * S + t0) * G + r;
    for (int tt = 0; tt < 32; ++tt) {
        float a0 = 0.f, a1 = 0.f, a2 = 0.f, a3 = 0.f;
        #pragma unroll
        for (int k = 0; k < 64; k += 4) {
            float4 h4 = *(const float4*)(xs + tt * E + k);   // LDS broadcast
            a0 = fmaf(w[k],   h4.x, a0);
            a1 = fmaf(w[k+1], h4.y, a1);
            a2 = fmaf(w[k+2], h4.z, a2);
            a3 = fmaf(w[k+3], h4.w, a3);
        }
        psum[tid] = (a0 + a1) + (a2 + a3);
        __syncthreads();
        if (tid < 256)
            outb[(size_t)tt * G] = bias +
                ((psum[idx] + psum[idx + 256]) + (psum[idx + 512] + psum[idx + 768]));
        __syncthreads();                          // psum reused next tt
    }
}

// ---------------------------------------------------------------- LSTM scan
// 64 blocks; workers are bid%8==0 (round-robin dispatch -> same XCD), role =
// bid/8 -> (b = role&3, dir = role>>2). Block (b,dir) owns h [b*64, b*64+64)
// = 256 gate rows. 1024 threads: (q=tid>>8, idx=tid&255): gate row
// (idx>>6)*256 + b*64 + (idx&63), k-range q*64..q*64+64 (w[64] in regs).
__global__ __launch_bounds__(1024, 4) void lstm_scan_hs(
    const float* __restrict__ xg,                 // [2][S][G]
    const float* __restrict__ Whh_f,
    const float* __restrict__ Whh_b,
    float* __restrict__ out,                      // [S][512]
    unsigned long long* __restrict__ sb)
{
    const int bid = blockIdx.x;
    if (bid & 7) return;                          // non-workers exit
    const int role = bid >> 3;
    const int b   = role & 3;
    const int dir = role >> 2;
    const int tid = threadIdx.x;

    unsigned long long* hot     = sb;
    unsigned long long* slow    = sb + SB_SLOW;
    unsigned long long* hs_hot  = sb + SB_HSH;
    unsigned long long* hs_slow = sb + SB_HSS;
    int* ctr = (int*)(sb + SB_CTR);

    // ---- handshake: is the plain-store -> sc0-load path live between workers?
    __shared__ int s_fast;
    if (tid == 0) s_fast = 1;
    __syncthreads();
    if (tid == 0) {
        __hip_atomic_store(&hs_hot[role], MAGICV,
                           __ATOMIC_RELAXED, __HIP_MEMORY_SCOPE_WORKGROUP);
        __hip_atomic_store(&hs_slow[role], MAGICV,
                           __ATOMIC_RELAXED, __HIP_MEMORY_SCOPE_AGENT);
    }
    if (tid < 8 && tid != role) {
        bool seen = false;
        for (int it = 0; it < 1024 && !seen; ++it)
            seen = (ld_sc0_u64(&hs_hot[tid]) == MAGICV);
        if (!seen) s_fast = 0;                    // benign race: all write 0
        while (__hip_atomic_load(&hs_slow[tid], __ATOMIC_RELAXED,
                                 __HIP_MEMORY_SCOPE_AGENT) != MAGICV) {}
    }
    __syncthreads();
    int use_fast = s_fast;
    if (tid == 0) {                               // arrival barrier (8 workers)
        __hip_atomic_fetch_add(ctr, 1, __ATOMIC_RELAXED, __HIP_MEMORY_SCOPE_AGENT);
        while (__hip_atomic_load(ctr, __ATOMIC_RELAXED,
                                 __HIP_MEMORY_SCOPE_AGENT) < 8) {}
    }
    __syncthreads();

    // ---- weights
    const int q    = tid >> 8;
    const int idx  = tid & 255;
    const int gate = idx >> 6;
    const int hloc = idx & 63;
    const int hidx = b * 64 + hloc;
    const int row  = gate * Hh + hidx;
    const float* W   = dir ? Whh_b : Whh_f;
    const float* xgd = xg + (size_t)dir * S * G;

    float w[64];
    #pragma unroll
    for (int k = 0; k < 64; k += 4) {
        float4 v = *(const float4*)(W + (size_t)row * Hh + q * 64 + k);
        w[k] = v.x; w[k+1] = v.y; w[k+2] = v.z; w[k+3] = v.w;
    }

    __shared__ __align__(16) float h_lds[Hh];
    __shared__ float psum[1024];
    __shared__ float gates_lds[256];
    if (tid < Hh) h_lds[tid] = 0.f;
    float c = 0.f;

    const int t0 = dir ? (S - 1) : 0;
    const int dt = dir ? -1 : 1;
    float xg_c = 0.f, xg_n1 = 0.f;                // 2-deep prefetch
    if (tid < 256) {
        xg_c  = xgd[(size_t)t0 * G + row];
        xg_n1 = xgd[(size_t)(t0 + dt) * G + row];
    }
    const bool poller = (tid < Hh) && ((tid >> 6) != b);
    __syncthreads();

    for (int s = 0; s < S; ++s) {
        const int t = t0 + dt * s;
        float xg_n2 = 0.f;
        if (tid < 256 && s + 2 < S) xg_n2 = xgd[(size_t)(t + 2 * dt) * G + row];

        // partial matvec over this thread's k-quarter (wave-uniform LDS bcast)
        const float* hh = (const float*)h_lds + q * 64;
        float a0 = 0.f, a1 = 0.f, a2 = 0.f, a3 = 0.f;
        #pragma unroll
        for (int k = 0; k < 64; k += 4) {
            float4 h4 = *(const float4*)(hh + k);
            a0 = fmaf(w[k],   h4.x, a0);
            a1 = fmaf(w[k+1], h4.y, a1);
            a2 = fmaf(w[k+2], h4.z, a2);
            a3 = fmaf(w[k+3], h4.w, a3);
        }
        psum[tid] = (a0 + a1) + (a2 + a3);
        __syncthreads();                                     // partials ready

        if (tid < 256) {
            float acc = xg_c +
                ((psum[idx] + psum[idx + 256]) + (psum[idx + 512] + psum[idx + 768]));
            float a = (gate == 2) ? tanhf(acc) : 1.f / (1.f + expf(-acc));
            gates_lds[idx] = a;
        }
        __syncthreads();                                     // gates ready

        const int slot = ((dir << 1) | (s & 1)) << 8;
        const unsigned st = (unsigned)(s + 1);

        if (tid < 64) {                                      // wave 0: cell update
            float iv = gates_lds[hloc];
            float fv = gates_lds[64 + hloc];
            float gv = gates_lds[128 + hloc];
            float ov = gates_lds[192 + hloc];
            c = fv * c + iv * gv;
            float h = ov * tanhf(c);
            unsigned long long pw =
                ((unsigned long long)st << 32) | (unsigned long long)__float_as_uint(h);
            __hip_atomic_store(&hot[slot + hidx], pw,
                               __ATOMIC_RELAXED, __HIP_MEMORY_SCOPE_WORKGROUP);
            __hip_atomic_store(&slow[slot + hidx], pw,
                               __ATOMIC_RELAXED, __HIP_MEMORY_SCOPE_AGENT);
            out[(size_t)t * 512 + dir * Hh + hidx] = h;
            h_lds[hidx] = h;                                 // own segment direct
        }
        // poll peers' h words (stamped; fast path with sticky downgrade)
        if (s + 1 < S && poller) {
            unsigned long long v = 0; bool got = false;
            if (use_fast) {
                #pragma unroll 1
                for (int spins = 0; spins < 4096; ++spins) {
                    v = ld_sc0_u64(&hot[slot + tid]);
                    if ((unsigned)(v >> 32) == st) { got = true; break; }
                }
                if (!got) use_fast = 0;                      // permanent downgrade
            }
            if (!got) {
                do {
                    v = __hip_atomic_load(&slow[slot + tid], __ATOMIC_RELAXED,
                                          __HIP_MEMORY_SCOPE_AGENT);
                } while ((unsigned)(v >> 32) != st);
            }
            h_lds[tid] = __uint_as_float((unsigned)v);
        }
        __syncthreads();                                     // h(t) complete in LDS
        xg_c = xg_n1; xg_n1 = xg_n2;
    }
}

// ---------------------------------------------------------------- emissions
__global__ __launch_bounds__(256) void emissions_kernel(
    const float* __restrict__ lo,                 // [S][512]
    const float* __restrict__ Wout,               // [NT][512]
    const float* __restrict__ bout,
    float* __restrict__ em)                       // [S][NT]
{
    int gid = blockIdx.x * blockDim.x + threadIdx.x;
    if (gid >= S * NT) return;
    int t = gid / NT;
    int j = gid - t * NT;
    const float* x = lo + (size_t)t * 512;
    const float* w = Wout + (size_t)j * 512;
    float a0 = 0.f, a1 = 0.f, a2 = 0.f, a3 = 0.f;
    #pragma unroll 8
    for (int k = 0; k < 512; k += 4) {
        float4 xv = *(const float4*)(x + k);
        float4 wv = *(const float4*)(w + k);
        a0 = fmaf(xv.x, wv.x, a0);
        a1 = fmaf(xv.y, wv.y, a1);
        a2 = fmaf(xv.z, wv.z, a2);
        a3 = fmaf(xv.w, wv.w, a3);
    }
    em[gid] = bout[j] + ((a0 + a1) + (a2 + a3));
}

// ---------------------------------------------------------------- viterbi forward
// 64 lanes: lane = g*20 + j (g=0..2 active, lanes 60..63 spectators).
__global__ __launch_bounds__(64) void viterbi_fwd(
    const float* __restrict__ em,                 // [S][NT]
    const float* __restrict__ start_trans,
    const float* __restrict__ end_trans,
    const float* __restrict__ trans,              // [NT][NT] (from,to)
    unsigned char* __restrict__ bp,               // [S][NT]
    int* __restrict__ last_out)
{
    const int lane = threadIdx.x;
    const int g    = lane / 20;                   // 0,1,2 (3 = spectator)
    const int j    = lane - g * 20;               // to-tag (0..19 for g<3)
    const int i0   = g * 7;

    float tc[7];
    #pragma unroll
    for (int u = 0; u < 7; ++u) {
        int i = i0 + u;
        tc[u] = (g < 3 && i < 20) ? trans[i * NT + j] : -3.0e38f;
    }

    const int jj = (g < 3) ? j : 0;               // safe index for spectators
    float snew  = start_trans[jj] + em[jj];       // score(0)
    if (g == 0) bp[j] = (unsigned char)j;         // t=0: identity (never used)
    float e_cur = em[NT + jj];

    for (int t = 1; t < S; ++t) {
        float s_sub[7];
        #pragma unroll
        for (int u = 0; u < 7; ++u)
            s_sub[u] = __shfl(snew, i0 + u);      // sources are lanes 0..27
        float e_nxt = (t + 1 < S) ? em[(size_t)(t + 1) * NT + jj] : 0.f;

        float bv = s_sub[0] + tc[0];
        int   bi = i0;
        #pragma unroll
        for (int u = 1; u < 7; ++u) {
            float v = s_sub[u] + tc[u];
            if (v > bv) { bv = v; bi = i0 + u; }  // strict >: first-index in group
        }
        float v0 = __shfl(bv, jj), v1 = __shfl(bv, jj + 20), v2 = __shfl(bv, jj + 40);
        int   c0 = __shfl(bi, jj), c1 = __shfl(bi, jj + 20), c2 = __shfl(bi, jj + 40);
        float best = v0; int bidx = c0;
        if (v1 > best) { best = v1; bidx = c1; }
        if (v2 > best) { best = v2; bidx = c2; }
        snew = best + e_cur;
        if (g == 0) bp[(size_t)t * NT + j] = (unsigned char)bidx;
        e_cur = e_nxt;
    }

    float bv = __shfl(snew, 0) + end_trans[0];
    int   bi = 0;
    #pragma unroll 1
    for (int i = 1; i < 20; ++i) {
        float v = __shfl(snew, i) + end_trans[i];
        if (v > bv) { bv = v; bi = i; }
    }
    if (lane == 0) *last_out = bi;
}

// ---------------------------------------------------------------- backtrace
__global__ __launch_bounds__(64) void bt_maps(
    const unsigned char* __restrict__ bp, unsigned char* __restrict__ maps)
{
    __shared__ unsigned char lbp[CLEN * NT];
    const int c = blockIdx.x, tid = threadIdx.x;
    const unsigned* src = (const unsigned*)(bp + (size_t)c * CLEN * NT);
    unsigned* dst = (unsigned*)lbp;
    for (int q = tid; q < CLEN * NT / 4; q += 64) dst[q] = src[q];
    __syncthreads();
    if (tid < NT) {
        int x = tid;
        for (int t = CLEN - 1; t >= 0; --t) x = lbp[t * NT + x];
        maps[c * NT + tid] = (unsigned char)x;
    }
}

__global__ __launch_bounds__(64) void bt_boundary(
    const unsigned char* __restrict__ maps, const int* __restrict__ last_out,
    int* __restrict__ btags)
{
    __shared__ unsigned char m[NCHUNK * NT];
    const int tid = threadIdx.x;
    for (int q = tid; q < NCHUNK * NT; q += 64) m[q] = maps[q];
    __syncthreads();
    if (tid == 0) {
        int x = *last_out;
        btags[NCHUNK - 1] = x;
        for (int c = NCHUNK - 1; c >= 1; --c) {
            x = m[c * NT + x];
            btags[c - 1] = x;
        }
    }
}

__global__ __launch_bounds__(64) void bt_emit(
    const unsigned char* __restrict__ bp, const int* __restrict__ btags,
    int* __restrict__ path)
{
    __shared__ unsigned char lbp[CLEN * NT];
    const int c = blockIdx.x, tid = threadIdx.x;
    const unsigned* src = (const unsigned*)(bp + (size_t)c * CLEN * NT);
    unsigned* dst = (unsigned*)lbp;
    for (int q = tid; q < CLEN * NT / 4; q += 64) dst[q] = src[q];
    __syncthreads();
    if (tid == 0) {
        int x = btags[c];
        path[c * CLEN + CLEN - 1] = x;
        for (int t = CLEN - 1; t >= 1; --t) {
            x = lbp[t * NT + x];
            path[c * CLEN + t - 1] = x;
        }
    }
}

// ---------------------------------------------------------------- launcher
extern "C" void kernel_launch(void* const* d_in, const int* in_sizes, int n_in,
                              void* d_out, int out_size, void* d_ws, size_t ws_size,
                              hipStream_t stream) {
    const int*   sent   = (const int*)  d_in[0];
    const float* embed  = (const float*)d_in[1];
    const float* Wih_f  = (const float*)d_in[2];
    const float* Whh_f  = (const float*)d_in[3];
    const float* bih_f  = (const float*)d_in[4];
    const float* bhh_f  = (const float*)d_in[5];
    const float* Wih_b  = (const float*)d_in[6];
    const float* Whh_b  = (const float*)d_in[7];
    const float* bih_b  = (const float*)d_in[8];
    const float* bhh_b  = (const float*)d_in[9];
    const float* Wout   = (const float*)d_in[10];
    const float* bout   = (const float*)d_in[11];
    const float* start_trans = (const float*)d_in[12];
    const float* end_trans   = (const float*)d_in[13];
    const float* trans       = (const float*)d_in[14];
    int* path = (int*)d_out;

    char* ws = (char*)d_ws;
    size_t off = 0;
    float* xg = (float*)(ws + off); off += (size_t)2 * S * G * 4;   // 64 MB
    float* lo = (float*)(ws + off); off += (size_t)S * 512 * 4;     // 16 MB
    float* em = (float*)(ws + off); off += (size_t)S * NT * 4;      // 640 KB
    unsigned char* bp   = (unsigned char*)(ws + off); off += (size_t)S * NT;  // 160 KB
    unsigned char* maps = (unsigned char*)(ws + off); off += 4096;
    int* btags = (int*)(ws + off); off += 1024;
    int* lastp = (int*)(ws + off); off += 256;
    off = (off + 255) & ~(size_t)255;
    unsigned long long* sb = (unsigned long long*)(ws + off); off += SB_SIZE * 8;

    sync_init<<<dim3(1), 1024, 0, stream>>>(sb);
    xg_project<<<dim3(S / 32, 4, 2), 1024, 0, stream>>>(
        sent, embed, Wih_f, bih_f, bhh_f, Wih_b, bih_b, bhh_b, xg);
    lstm_scan_hs<<<dim3(64), 1024, 0, stream>>>(xg, Whh_f, Whh_b, lo, sb);
    emissions_kernel<<<dim3((S * NT + 255) / 256), 256, 0, stream>>>(lo, Wout, bout, em);
    viterbi_fwd<<<dim3(1), 64, 0, stream>>>(em, start_trans, end_trans, trans, bp, lastp);
    bt_maps<<<dim3(NCHUNK), 64, 0, stream>>>(bp, maps);
    bt_boundary<<<dim3(1), 64, 0, stream>>>(maps, lastp, btags);
    bt_emit<<<dim3(NCHUNK), 64, 0, stream>>>(bp, btags, path);
}